// Round 3
// baseline (30602.228 us; speedup 1.0000x reference)
//
#include <hip/hip_runtime.h>
#include <math.h>

#define B_ 128
#define S_ 256
#define I_ 512
#define H_ 1024
#define O_ 512
#define T_ 128
#define KB 32
#define NT_CELL 48   // 16 x-phase tiles (K=512) + 32 h-phase tiles (K=1024)
#define NT_PROJ 32   // K=1024

__device__ __forceinline__ float sigmoidf_(float x) {
    return 1.0f / (1.0f + expf(-x));
}

// Fused LSTM cell step.
// Grid 256 blocks x 256 threads. Block owns units j0..j0+3 (16 gate rows), all 128 batch.
// Thread (tb = tid&127, tj = tid>>7): batch tb, units {j0+2tj, j0+2tj+1}, all 4 gates each
//   -> 8 accumulators; per k: 1 b32 a-read + 2 wave-uniform b128 w-reads + 8 FMA.
// Double-buffered LDS tiles with register prefetch: 1 barrier per K-tile.
__global__ __launch_bounds__(256) void lstm_cell_kernel(
    const float* __restrict__ A1, int lda1,   // [128 x 512] (x_t with lda S*I, or y with lda O)
    const float* __restrict__ Wih,            // [4H x 512]
    const float* __restrict__ Whh,            // [4H x 1024]
    const float* __restrict__ bsum,           // [4H]
    const float* __restrict__ hin,            // [128 x 1024]
    float* __restrict__ hout,                 // [128 x 1024]
    float* __restrict__ c)                    // [128 x 1024] in/out
{
    __shared__ float As[2][B_][33];   // [buf][b][k] pad 33 -> bank (b+k)%32, 2 lanes/bank = free
    __shared__ float Ws[2][KB][16];   // [buf][k][r'], r' = tj*8 + u*4 + g (row 64B, float4-aligned)
    __shared__ float ht[B_][5];       // epilogue exchange (pad 5: conflict-free)
    __shared__ float ct[B_][5];

    const int tid = threadIdx.x;
    const int tb  = tid & 127;
    const int tj  = tid >> 7;          // 0..1
    const int j0  = blockIdx.x * 4;

    // W staging ids (tid < 128): r' = tid&15, q = (tid>>4)&7
    const int wr  = tid & 15;
    const int wq  = (tid >> 4) & 7;
    // decode r' -> global gate row: g = wr&3, u = (wr>>2)&1, tjs = wr>>3
    const int grow = (wr & 3) * H_ + j0 + 2 * (wr >> 3) + ((wr >> 2) & 1);

    float acc[2][4];
#pragma unroll
    for (int u = 0; u < 2; ++u)
#pragma unroll
        for (int g = 0; g < 4; ++g)
            acc[u][g] = bsum[g * H_ + j0 + 2 * tj + u];

    float4 pa[4];
    float4 pw;

    auto load_tile = [&](int t) {
        const float* A; int lda; const float* W; int ldw; int k0;
        if (t < 16) { A = A1;  lda = lda1; W = Wih; ldw = I_; k0 = t * KB; }
        else        { A = hin; lda = H_;  W = Whh; ldw = H_; k0 = (t - 16) * KB; }
#pragma unroll
        for (int rep = 0; rep < 4; ++rep) {
            const int flat = tid + rep * 256;           // 0..1023
            pa[rep] = *reinterpret_cast<const float4*>(
                A + (size_t)(flat >> 3) * lda + k0 + ((flat & 7) << 2));
        }
        if (tid < 128) {
            pw = *reinterpret_cast<const float4*>(
                W + (size_t)grow * ldw + k0 + (wq << 2));
        }
    };

    auto write_tile = [&](int p) {
#pragma unroll
        for (int rep = 0; rep < 4; ++rep) {
            const int flat = tid + rep * 256;
            const int b = flat >> 3;
            const int q = (flat & 7) << 2;
            As[p][b][q + 0] = pa[rep].x;
            As[p][b][q + 1] = pa[rep].y;
            As[p][b][q + 2] = pa[rep].z;
            As[p][b][q + 3] = pa[rep].w;
        }
        if (tid < 128) {
            const int kk = wq << 2;
            Ws[p][kk + 0][wr] = pw.x;
            Ws[p][kk + 1][wr] = pw.y;
            Ws[p][kk + 2][wr] = pw.z;
            Ws[p][kk + 3][wr] = pw.w;
        }
    };

    load_tile(0);
    write_tile(0);
    __syncthreads();

    int p = 0;
    for (int t = 0; t < NT_CELL; ++t) {
        if (t + 1 < NT_CELL) load_tile(t + 1);   // global -> regs, lands during inner
#pragma unroll
        for (int k = 0; k < KB; ++k) {
            const float a = As[p][tb][k];
            const float4 w0 = *reinterpret_cast<const float4*>(&Ws[p][k][tj * 8]);
            const float4 w1 = *reinterpret_cast<const float4*>(&Ws[p][k][tj * 8 + 4]);
            acc[0][0] = fmaf(a, w0.x, acc[0][0]);
            acc[0][1] = fmaf(a, w0.y, acc[0][1]);
            acc[0][2] = fmaf(a, w0.z, acc[0][2]);
            acc[0][3] = fmaf(a, w0.w, acc[0][3]);
            acc[1][0] = fmaf(a, w1.x, acc[1][0]);
            acc[1][1] = fmaf(a, w1.y, acc[1][1]);
            acc[1][2] = fmaf(a, w1.z, acc[1][2]);
            acc[1][3] = fmaf(a, w1.w, acc[1][3]);
        }
        if (t + 1 < NT_CELL) write_tile(p ^ 1);  // other buffer: no hazard with inner readers
        __syncthreads();
        p ^= 1;
    }

    // ---- epilogue: LDS exchange for coalesced float4 c/h update ----
    if (tid < 128) {
        const float4 cv = *reinterpret_cast<const float4*>(&c[(size_t)tid * H_ + j0]);
        ct[tid][0] = cv.x; ct[tid][1] = cv.y; ct[tid][2] = cv.z; ct[tid][3] = cv.w;
    }
    __syncthreads();
#pragma unroll
    for (int u = 0; u < 2; ++u) {
        const int s = tj * 2 + u;
        const float iv = sigmoidf_(acc[u][0]);
        const float fv = sigmoidf_(acc[u][1]);
        const float gv = tanhf(acc[u][2]);
        const float ov = sigmoidf_(acc[u][3]);
        const float cn = fv * ct[tb][s] + iv * gv;   // slot owned by exactly this thread
        ct[tb][s] = cn;
        ht[tb][s] = ov * tanhf(cn);
    }
    __syncthreads();
    if (tid < 128) {
        float4 co, ho;
        co.x = ct[tid][0]; co.y = ct[tid][1]; co.z = ct[tid][2]; co.w = ct[tid][3];
        ho.x = ht[tid][0]; ho.y = ht[tid][1]; ho.z = ht[tid][2]; ho.w = ht[tid][3];
        *reinterpret_cast<float4*>(&c[(size_t)tid * H_ + j0])    = co;
        *reinterpret_cast<float4*>(&hout[(size_t)tid * H_ + j0]) = ho;
    }
}

// y[b,o] = h[b,:] @ Wp[o,:] + bp[o] -> feedback buffer + d_out[:, t, :].
// Grid 128 = 64 o-groups (8 outs) x 2 batch halves; 256 threads.
// Thread (tb = tid&63, th = tid>>6): batch bh*64+tb, outs {o0+2th, o0+2th+1}.
__global__ __launch_bounds__(256) void proj_kernel(
    const float* __restrict__ h,      // [128 x 1024]
    const float* __restrict__ Wp,     // [512 x 1024]
    const float* __restrict__ bp,     // [512]
    float* __restrict__ yfb,          // [128 x 512]
    float* __restrict__ out_t)        // d_out + t*O_, batch stride T_*O_
{
    __shared__ float Hs[2][64][33];
    __shared__ float Ps[2][KB][8];    // [buf][k][o-local]
    __shared__ float yt[64][9];

    const int tid = threadIdx.x;
    const int tb  = tid & 63;
    const int th  = tid >> 6;          // 0..3
    const int bh  = blockIdx.x >> 6;   // 0..1
    const int o0  = (blockIdx.x & 63) * 8;

    const int pr = tid & 7;
    const int pq = (tid >> 3) & 7;

    float acc0 = 0.f, acc1 = 0.f;
    float4 pa[2];
    float4 pw;

    auto load_tile = [&](int t) {
        const int k0 = t * KB;
#pragma unroll
        for (int rep = 0; rep < 2; ++rep) {
            const int flat = tid + rep * 256;           // 0..511
            pa[rep] = *reinterpret_cast<const float4*>(
                h + (size_t)(bh * 64 + (flat >> 3)) * H_ + k0 + ((flat & 7) << 2));
        }
        if (tid < 64) {
            pw = *reinterpret_cast<const float4*>(
                Wp + (size_t)(o0 + pr) * H_ + k0 + (pq << 2));
        }
    };
    auto write_tile = [&](int p) {
#pragma unroll
        for (int rep = 0; rep < 2; ++rep) {
            const int flat = tid + rep * 256;
            const int bb = flat >> 3;
            const int q = (flat & 7) << 2;
            Hs[p][bb][q + 0] = pa[rep].x;
            Hs[p][bb][q + 1] = pa[rep].y;
            Hs[p][bb][q + 2] = pa[rep].z;
            Hs[p][bb][q + 3] = pa[rep].w;
        }
        if (tid < 64) {
            const int kk = pq << 2;
            Ps[p][kk + 0][pr] = pw.x;
            Ps[p][kk + 1][pr] = pw.y;
            Ps[p][kk + 2][pr] = pw.z;
            Ps[p][kk + 3][pr] = pw.w;
        }
    };

    load_tile(0);
    write_tile(0);
    __syncthreads();

    int p = 0;
    for (int t = 0; t < NT_PROJ; ++t) {
        if (t + 1 < NT_PROJ) load_tile(t + 1);
#pragma unroll
        for (int k = 0; k < KB; ++k) {
            const float a = Hs[p][tb][k];
            const float2 w = *reinterpret_cast<const float2*>(&Ps[p][k][th * 2]);
            acc0 = fmaf(a, w.x, acc0);
            acc1 = fmaf(a, w.y, acc1);
        }
        if (t + 1 < NT_PROJ) write_tile(p ^ 1);
        __syncthreads();
        p ^= 1;
    }

    yt[tb][th * 2 + 0] = acc0 + bp[o0 + th * 2 + 0];
    yt[tb][th * 2 + 1] = acc1 + bp[o0 + th * 2 + 1];
    __syncthreads();
    if (tid < 128) {
        const int bb = tid >> 1;
        const int half = (tid & 1) * 4;
        float4 v;
        v.x = yt[bb][half + 0]; v.y = yt[bb][half + 1];
        v.z = yt[bb][half + 2]; v.w = yt[bb][half + 3];
        const int gb = bh * 64 + bb;
        *reinterpret_cast<float4*>(&yfb[(size_t)gb * O_ + o0 + half]) = v;
        *reinterpret_cast<float4*>(&out_t[(size_t)gb * (T_ * O_) + o0 + half]) = v;
    }
}

__global__ void bias_sum_kernel(
    const float* __restrict__ bi_e, const float* __restrict__ bh_e,
    const float* __restrict__ bi_d, const float* __restrict__ bh_d,
    float* __restrict__ be, float* __restrict__ bd)
{
    const int n = blockIdx.x * 256 + threadIdx.x;
    if (n < 4 * H_) {
        be[n] = bi_e[n] + bh_e[n];
        bd[n] = bi_d[n] + bh_d[n];
    }
}

extern "C" void kernel_launch(void* const* d_in, const int* in_sizes, int n_in,
                              void* d_out, int out_size, void* d_ws, size_t ws_size,
                              hipStream_t stream) {
    const float* x     = (const float*)d_in[0];
    // d_in[1] = tgt_len (compile-time T_ = 128)
    const float* Wih_e = (const float*)d_in[2];
    const float* Whh_e = (const float*)d_in[3];
    const float* bih_e = (const float*)d_in[4];
    const float* bhh_e = (const float*)d_in[5];
    const float* Wih_d = (const float*)d_in[6];
    const float* Whh_d = (const float*)d_in[7];
    const float* bih_d = (const float*)d_in[8];
    const float* bhh_d = (const float*)d_in[9];
    const float* Wp    = (const float*)d_in[10];
    const float* bp    = (const float*)d_in[11];
    float* out = (float*)d_out;
    float* ws  = (float*)d_ws;

    // workspace (floats):
    // [h0: 131072][c: 131072][y: 65536][h1: 131072][be: 4096][bd: 4096]
    float* h0 = ws;
    float* c  = ws + 131072;
    float* y  = ws + 262144;
    float* h1 = ws + 327680;
    float* be = ws + 458752;
    float* bd = ws + 462848;

    // zero h0, c, y (contiguous prefix; ws is re-poisoned before every call)
    hipMemsetAsync(ws, 0, (size_t)327680 * sizeof(float), stream);
    bias_sum_kernel<<<16, 256, 0, stream>>>(bih_e, bhh_e, bih_d, bhh_d, be, bd);

    float* hin  = h0;
    float* hout = h1;

    // ---- encoder ----
    for (int t = 0; t < S_; ++t) {
        lstm_cell_kernel<<<256, 256, 0, stream>>>(
            x + (size_t)t * I_, S_ * I_, Wih_e, Whh_e, be, hin, hout, c);
        float* tmp = hin; hin = hout; hout = tmp;
    }

    // ---- decoder ----
    for (int t = 0; t < T_; ++t) {
        lstm_cell_kernel<<<256, 256, 0, stream>>>(
            y, O_, Wih_d, Whh_d, bd, hin, hout, c);
        float* tmp = hin; hin = hout; hout = tmp;
        proj_kernel<<<128, 256, 0, stream>>>(
            hin, Wp, bp, y, out + (size_t)t * O_);
    }
}